// Round 11
// baseline (268.137 us; speedup 1.0000x reference)
//
#include <hip/hip_runtime.h>
#include <hip/hip_bf16.h>

#define SEQ 2048
#define DMODEL 2048
#define NHEAD 8
#define DHEAD 256

typedef _Float16 v8h __attribute__((ext_vector_type(8)));
typedef unsigned short v8u __attribute__((ext_vector_type(8)));
typedef float v4f __attribute__((ext_vector_type(4)));

__device__ __forceinline__ float b2f(unsigned short s) {
    return __uint_as_float(((unsigned)s) << 16);
}
__device__ __forceinline__ unsigned short f2b(float f) {
    unsigned u = __float_as_uint(f);
    u += 0x7fffu + ((u >> 16) & 1u);   // RNE
    return (unsigned short)(u >> 16);
}
__device__ __forceinline__ unsigned short f2h(float f) {
    _Float16 h = (_Float16)f;
    return __builtin_bit_cast(unsigned short, h);
}
__device__ __forceinline__ float h2f(unsigned short s) {
    return (float)__builtin_bit_cast(_Float16, s);
}

// ---------------------------------------------------------------- detect dtype
// ONE block (round-0 proven). Consumers read the flag -> no 2048-block
// hammering of the same 4KB of q (suspected L2-slice serializer in k_cvt).
__global__ __launch_bounds__(256) void k_detect(const unsigned short* q, int* flag) {
    __shared__ int cnt;
    if (threadIdx.x == 0) cnt = 0;
    __syncthreads();
    int wild = 0;
    for (int i = threadIdx.x; i < 2048; i += 256) {
        float x = b2f(q[i]);
        float ax = fabsf(x);
        if (!(ax <= 100.0f) || (x != 0.0f && ax < 1e-6f)) wild++;
    }
    atomicAdd(&cnt, wild);
    __syncthreads();
    if (threadIdx.x == 0) *flag = (cnt < 256) ? 1 : 0;  // 1 = bf16, 0 = f32
}

// --------------------------------------------------------------- streaming cvt
// [0,1024):    q,k -> fp16 (vectorized both dtypes)
// [1024,2048): v -> vT[h][d][s] fp16 (LDS 64x64 tile transpose)
// Flag-based dtype (single broadcast scalar read per block).
__global__ __launch_bounds__(256) void k_cvt(const void* q, const void* k, const void* v,
                                             const int* flag,
                                             unsigned short* qb, unsigned short* kb,
                                             unsigned short* vT) {
    __shared__ unsigned short tile[64][72];
    const int tid = threadIdx.x;
    const int b = blockIdx.x;
    const int bf = *(volatile const int*)flag;

    if (b < 1024) {
        // ---------------- q,k -> fp16 (16 elems per thread per tensor)
        size_t i0 = ((size_t)b * 256 + tid) * 16;
        if (bf) {
            const unsigned short* qp = (const unsigned short*)q;
            const unsigned short* kp = (const unsigned short*)k;
#pragma unroll
            for (int hlf = 0; hlf < 2; hlf++) {
                v8u uq = *(const v8u*)(qp + i0 + hlf * 8);
                v8u uk = *(const v8u*)(kp + i0 + hlf * 8);
                v8u oq, ok;
#pragma unroll
                for (int j = 0; j < 8; j++) { oq[j] = f2h(b2f(uq[j])); ok[j] = f2h(b2f(uk[j])); }
                *(v8u*)(qb + i0 + hlf * 8) = oq;
                *(v8u*)(kb + i0 + hlf * 8) = ok;
            }
        } else {
            const float* qf = (const float*)q;
            const float* kf = (const float*)k;
#pragma unroll
            for (int hlf = 0; hlf < 2; hlf++) {
                v4f q0 = *(const v4f*)(qf + i0 + hlf * 8);
                v4f q1 = *(const v4f*)(qf + i0 + hlf * 8 + 4);
                v4f k0 = *(const v4f*)(kf + i0 + hlf * 8);
                v4f k1 = *(const v4f*)(kf + i0 + hlf * 8 + 4);
                v8u oq, ok;
#pragma unroll
                for (int j = 0; j < 4; j++) {
                    oq[j] = f2h(q0[j]); oq[4 + j] = f2h(q1[j]);
                    ok[j] = f2h(k0[j]); ok[4 + j] = f2h(k1[j]);
                }
                *(v8u*)(qb + i0 + hlf * 8) = oq;
                *(v8u*)(kb + i0 + hlf * 8) = ok;
            }
        }
    } else {
        // ---------------- v -> vT (64x64 tile transpose)
        int b2 = b - 1024;
        int s0 = (b2 & 31) * 64, d0 = (b2 >> 5) * 64;
        int r = tid >> 2, c0 = (tid & 3) * 16;
        size_t base = (size_t)(s0 + r) * DMODEL + d0 + c0;
        if (bf) {
            const unsigned short* vp = (const unsigned short*)v;
            v8u a = *(const v8u*)(vp + base);
            v8u bb = *(const v8u*)(vp + base + 8);
#pragma unroll
            for (int j = 0; j < 8; j++) { tile[r][c0 + j] = f2h(b2f(a[j])); tile[r][c0 + 8 + j] = f2h(b2f(bb[j])); }
        } else {
            const float* vp = (const float*)v;
            v4f a0 = *(const v4f*)(vp + base);
            v4f a1 = *(const v4f*)(vp + base + 4);
            v4f a2 = *(const v4f*)(vp + base + 8);
            v4f a3 = *(const v4f*)(vp + base + 12);
#pragma unroll
            for (int j = 0; j < 4; j++) {
                tile[r][c0 + j] = f2h(a0[j]);      tile[r][c0 + 4 + j] = f2h(a1[j]);
                tile[r][c0 + 8 + j] = f2h(a2[j]);  tile[r][c0 + 12 + j] = f2h(a3[j]);
            }
        }
        __syncthreads();
        int dr = tid >> 2, sc0 = (tid & 3) * 16;
        v8u o0, o1;
#pragma unroll
        for (int j = 0; j < 8; j++) { o0[j] = tile[sc0 + j][dr]; o1[j] = tile[sc0 + 8 + j][dr]; }
        int head = d0 >> 8;
        int dh = (d0 & 255) + dr;
        size_t ob = ((size_t)head * DHEAD + dh) * SEQ + s0 + sc0;
        *(v8u*)(vT + ob) = o0;
        *(v8u*)(vT + ob + 8) = o1;
    }
}

// --------------------------------------------- gate pre-activations
// Round-0 proven structure: block = 32 rows x 768-d chunk; x staged in LDS
// (coalesced); weight access (gd0+j)*8+hh depends only on hh -> single
// broadcast transaction per load, L1-resident. atomicAdd into zeroed ipre/fpre.
__global__ __launch_bounds__(256) void k_gates(const unsigned short* __restrict__ qb,
                                               const unsigned short* __restrict__ kb,
                                               const void* __restrict__ v,
                                               const void* __restrict__ igk,
                                               const void* __restrict__ fgk,
                                               const int* flag,
                                               float* ipre, float* fpre) {
    __shared__ float x_lds[32][68];
    const int bf = *(volatile const int*)flag;
    const int s0 = blockIdx.x * 32;
    const int c  = blockIdx.y;
    const int tid = threadIdx.x;
    const int sl = tid >> 3, hh = tid & 7;
    const int rr = tid >> 3, j0 = (tid & 7) * 8;
    float accI = 0.f, accF = 0.f;
    const unsigned short* ik16 = (const unsigned short*)igk;
    const unsigned short* fk16 = (const unsigned short*)fgk;
    const float* ik32 = (const float*)igk;
    const float* fk32 = (const float*)fgk;

    for (int wd = 0; wd < 12; ++wd) {
        const int gd0 = c * 768 + wd * 64;
        __syncthreads();    // prior chunk fully consumed
        {
            float xv[8];
            if (gd0 < 4096) {
                const unsigned short* sp = (gd0 < 2048) ? qb : kb;
                const int off = (gd0 < 2048) ? gd0 : gd0 - 2048;
                v8u a = *(const v8u*)(sp + (size_t)(s0 + rr) * DMODEL + off + j0);
#pragma unroll
                for (int j = 0; j < 8; j++) xv[j] = h2f(a[j]);
            } else if (bf) {
                const unsigned short* vp = (const unsigned short*)v;
                v8u a = *(const v8u*)(vp + (size_t)(s0 + rr) * DMODEL + (gd0 - 4096) + j0);
#pragma unroll
                for (int j = 0; j < 8; j++) xv[j] = b2f(a[j]);
            } else {
                const float* vp = (const float*)v;
                const size_t base = (size_t)(s0 + rr) * DMODEL + (gd0 - 4096) + j0;
                v4f a0 = *(const v4f*)(vp + base);
                v4f a1 = *(const v4f*)(vp + base + 4);
#pragma unroll
                for (int j = 0; j < 4; j++) { xv[j] = a0[j]; xv[4 + j] = a1[j]; }
            }
#pragma unroll
            for (int j = 0; j < 8; j++) x_lds[rr][j0 + j] = xv[j];
        }
        __syncthreads();
        if (bf) {
#pragma unroll 8
            for (int j = 0; j < 64; j++) {
                float x = x_lds[sl][j];
                int wi = (gd0 + j) * NHEAD + hh;
                accI += x * b2f(ik16[wi]);
                accF += x * b2f(fk16[wi]);
            }
        } else {
#pragma unroll 8
            for (int j = 0; j < 64; j++) {
                float x = x_lds[sl][j];
                int wi = (gd0 + j) * NHEAD + hh;
                accI += x * ik32[wi];
                accF += x * fk32[wi];
            }
        }
    }
    atomicAdd(&ipre[hh * SEQ + s0 + sl], accI);
    atomicAdd(&fpre[hh * SEQ + s0 + sl], accF);
}

// ---------------- per-head scans: cum(log_sigmoid(f)), a = i - cum, prefix-max
// shfl-based scans (verified in rounds 6/8/10): 2 barriers total.
__global__ __launch_bounds__(256) void k_scan(const float* ipre, const float* fpre,
                                              const void* ib_, const void* fb_,
                                              const int* flag,
                                              float* a_g, float* amax_g, float* nfl_g) {
    __shared__ float wtot[4], wmax[4];
    int bf = *(volatile const int*)flag;
    int h = blockIdx.x, tid = threadIdx.x;
    int lane = tid & 63, wv = tid >> 6;
    float ib = bf ? b2f(((const unsigned short*)ib_)[h]) : ((const float*)ib_)[h];
    float fb = bf ? b2f(((const unsigned short*)fb_)[h]) : ((const float*)fb_)[h];
    int s0 = tid * 8;
    float lf[8], ip[8];
#pragma unroll
    for (int j = 0; j < 8; j++) {
        float fp = fpre[h * SEQ + s0 + j] + fb;
        lf[j] = fminf(fp, 0.0f) - log1pf(__expf(-fabsf(fp)));
        ip[j] = ipre[h * SEQ + s0 + j] + ib;
    }
    float cs[8]; float t = 0.f;
#pragma unroll
    for (int j = 0; j < 8; j++) { t += lf[j]; cs[j] = t; }
    // inclusive wave scan (sum)
    float incl = t;
#pragma unroll
    for (int o = 1; o < 64; o <<= 1) {
        float n = __shfl_up(incl, o, 64);
        if (lane >= o) incl += n;
    }
    if (lane == 63) wtot[wv] = incl;
    __syncthreads();
    float wpre = 0.f;
#pragma unroll
    for (int i2 = 0; i2 < 4; i2++) if (i2 < wv) wpre += wtot[i2];
    float excl = wpre + incl - t;
    float cum[8], av[8];
#pragma unroll
    for (int j = 0; j < 8; j++) { cum[j] = excl + cs[j]; av[j] = ip[j] - cum[j]; }
    float mx = av[0];
#pragma unroll
    for (int j = 1; j < 8; j++) mx = fmaxf(mx, av[j]);
    // inclusive wave scan (max)
    float mincl = mx;
#pragma unroll
    for (int o = 1; o < 64; o <<= 1) {
        float n = __shfl_up(mincl, o, 64);
        if (lane >= o) mincl = fmaxf(mincl, n);
    }
    if (lane == 63) wmax[wv] = mincl;
    __syncthreads();
    float wpm = -3.0e38f;
#pragma unroll
    for (int i2 = 0; i2 < 4; i2++) if (i2 < wv) wpm = fmaxf(wpm, wmax[i2]);
    float up = __shfl_up(mincl, 1, 64);
    float run = fmaxf(wpm, (lane > 0) ? up : -3.0e38f);
#pragma unroll
    for (int j = 0; j < 8; j++) {
        run = fmaxf(run, av[j]);
        int s = s0 + j;
        a_g[h * SEQ + s]    = av[j];
        amax_g[h * SEQ + s] = run;
        float m = cum[j] + run;
        nfl_g[h * SEQ + s]  = __expf(fminf(fmaxf(-m, -60.f), 60.f));
    }
}

// --------------------------------------------------------------- main kernel
// Round-10 structure with the ones-column normalizer MFMAs replaced by an
// f32 shfl row-sum at P-write time (scheme correctness-proven in round 3):
// removes 8 MFMAs from the critical wave (w3: 24->16), deletes the 16 ghost
// vT rows (LDS 44032 -> ~43008), and makes rs f32-exact.
__global__ __launch_bounds__(256, 3) void k_main(const unsigned short* __restrict__ qb,
                                                 const unsigned short* __restrict__ kb,
                                                 const unsigned short* __restrict__ vT,
                                                 const float* __restrict__ a_g,
                                                 const float* __restrict__ amax_g,
                                                 float* __restrict__ h_buf,
                                                 float* __restrict__ rs_buf) {
    __shared__ __align__(16) unsigned short k_lds[32][264];
    __shared__ __align__(16) unsigned short vT_lds[256][40];
    __shared__ __align__(16) unsigned short P_lds[32][40];
    __shared__ __align__(16) unsigned short Plo_lds[32][40];
    __shared__ float a_s[32], amax_t[32], rs_acc[32];

    const int h   = blockIdx.x;
    const int y   = blockIdx.y;        // quota index within head, 0..95
    const int tid = threadIdx.x;
    const int lane = tid & 63;
    const int w   = tid >> 6;          // wave 0..3
    const int l15 = lane & 15;
    const int qd  = (lane >> 4) & 3;   // quad
    const int hd0 = h * DHEAD;

    // ---- quota: units [u, u_end) of this head's flattened triangle
    int u         = (y * 2080) / 96;
    int remaining = ((y + 1) * 2080) / 96 - u;
    int tile = (int)((sqrtf(8.0f * (float)u + 1.0f) - 1.0f) * 0.5f);
    while ((tile + 1) * (tile + 2) / 2 <= u) ++tile;
    while (tile * (tile + 1) / 2 > u) --tile;
    int js = u - tile * (tile + 1) / 2;
    bool needQ = true;

    if (tid < 32) rs_acc[tid] = 0.f;

    const v4f vzero = {0.f, 0.f, 0.f, 0.f};
    v4f acc[2][4];
#pragma unroll
    for (int m = 0; m < 2; m++)
#pragma unroll
        for (int n = 0; n < 4; n++) acc[m][n] = vzero;

    const int mw = w >> 1, nw = w & 1;
    const int krow = tid >> 3, kc0 = (tid & 7) * 32;

    // Q fragment in registers: this wave's 16 rows x its qd-column slices
    v8u qr[8];

    // staging registers (async-split: load early, ds_write late)
    v8u kr0, kr1, kr2, kr3, vr0, vr1, vr2, vr3;
    float areg = 0.f;
    {   // prefetch first unit
        const int s0 = js * 32;
        const unsigned short* ks = kb + (size_t)(s0 + krow) * DMODEL + hd0 + kc0;
        kr0 = *(const v8u*)(ks);      kr1 = *(const v8u*)(ks + 8);
        kr2 = *(const v8u*)(ks + 16); kr3 = *(const v8u*)(ks + 24);
        const unsigned short* vs = vT + (size_t)(hd0 + tid) * SEQ + s0;
        vr0 = *(const v8u*)(vs);      vr1 = *(const v8u*)(vs + 8);
        vr2 = *(const v8u*)(vs + 16); vr3 = *(const v8u*)(vs + 24);
        if (tid < 32) areg = a_g[h * SEQ + s0 + tid];
    }

    for (;;) {
        const int t0 = tile * 32;
        __syncthreads();   // previous unit consumed k/vT/P
        if (needQ) {       // new tile: Q fragment -> registers + per-row stabilizer
            const unsigned short* src = qb + (size_t)(t0 + mw * 16 + l15) * DMODEL + hd0 + qd * 8;
#pragma unroll
            for (int i = 0; i < 8; i++)
                qr[i] = *(const v8u*)(src + i * 32);
            if (tid < 32) amax_t[tid] = amax_g[h * SEQ + t0 + tid];
            needQ = false;
        }
        *(v8u*)&k_lds[krow][kc0]      = kr0;
        *(v8u*)&k_lds[krow][kc0 + 8]  = kr1;
        *(v8u*)&k_lds[krow][kc0 + 16] = kr2;
        *(v8u*)&k_lds[krow][kc0 + 24] = kr3;
        *(v8u*)&vT_lds[tid][0]  = vr0;
        *(v8u*)&vT_lds[tid][8]  = vr1;
        *(v8u*)&vT_lds[tid][16] = vr2;
        *(v8u*)&vT_lds[tid][24] = vr3;
        if (tid < 32) a_s[tid] = areg;
        __syncthreads();

        // QK^T: each wave computes one 16x16 tile of P (mw,nw); A from registers
        v4f c = vzero;
#pragma unroll
        for (int i = 0; i < 8; i++) {
            v8h a = __builtin_bit_cast(v8h, qr[i]);
            v8h b = *(const v8h*)&k_lds[nw * 16 + l15][i * 32 + qd * 8];
            c = __builtin_amdgcn_mfma_f32_16x16x32_f16(a, b, c, 0, 0, 0);
        }
        // decay + causal mask; P as fp16 hi/lo; f32 row-sum via quad shfl
        {
            const bool diag = (js == tile);
            const int col = nw * 16 + l15;
            const float av = a_s[col];
#pragma unroll
            for (int r = 0; r < 4; r++) {
                int row = mw * 16 + qd * 4 + r;
                float arg = fminf(av - amax_t[row], 0.0f);
                float val = c[r] * 0.0625f * __expf(arg);   // 1/sqrt(256) folded here
                if (diag && col > row) val = 0.0f;
                unsigned short hi = f2h(val);
                float lo = val - h2f(hi);
                P_lds[row][col]   = hi;
                Plo_lds[row][col] = f2h(lo);
                float s = val;                               // f32 row-sum over 16 cols
                s += __shfl_xor(s, 1, 64);
                s += __shfl_xor(s, 2, 64);
                s += __shfl_xor(s, 4, 64);
                s += __shfl_xor(s, 8, 64);
                if (l15 == 0) atomicAdd(&rs_acc[row], s);
            }
        }
        __syncthreads();

        // prefetch NEXT unit now; HBM/L2 latency hides under the PV phase below
        int ntile = tile, njs = js + 1; bool nq = false;
        if (njs > tile) { ntile = tile + 1; njs = 0; nq = true; }
        if (remaining > 1) {
            const int s0 = njs * 32;
            const unsigned short* ks = kb + (size_t)(s0 + krow) * DMODEL + hd0 + kc0;
            kr0 = *(const v8u*)(ks);      kr1 = *(const v8u*)(ks + 8);
            kr2 = *(const v8u*)(ks + 16); kr3 = *(const v8u*)(ks + 24);
            const unsigned short* vs = vT + (size_t)(hd0 + tid) * SEQ + s0;
            vr0 = *(const v8u*)(vs);      vr1 = *(const v8u*)(vs + 8);
            vr2 = *(const v8u*)(vs + 16); vr3 = *(const v8u*)(vs + 24);
            if (tid < 32) areg = a_g[h * SEQ + s0 + tid];
        }

        // P @ V (hi + lo): wave w owns output cols [w*64, w*64+64)
        v8h aH0 = *(const v8h*)&P_lds[l15][qd * 8];
        v8h aH1 = *(const v8h*)&P_lds[16 + l15][qd * 8];
        v8h aL0 = *(const v8h*)&Plo_lds[l15][qd * 8];
        v8h aL1 = *(const v8h*)&Plo_lds[16 + l15][qd * 8];
#pragma unroll
        for (int nn = 0; nn < 4; nn++) {
            v8h bV = *(const v8h*)&vT_lds[w * 64 + nn * 16 + l15][qd * 8];
            acc[0][nn] = __builtin_amdgcn_mfma_f32_16x16x32_f16(aH0, bV, acc[0][nn], 0, 0, 0);
            acc[0][nn] = __builtin_amdgcn_mfma_f32_16x16x32_f16(aL0, bV, acc[0][nn], 0, 0, 0);
            acc[1][nn] = __builtin_amdgcn_mfma_f32_16x16x32_f16(aH1, bV, acc[1][nn], 0, 0, 0);
            acc[1][nn] = __builtin_amdgcn_mfma_f32_16x16x32_f16(aL1, bV, acc[1][nn], 0, 0, 0);
        }

        // flush at tile end or quota end (raw partials; fire-and-forget atomics)
        if (js == tile || remaining == 1) {
#pragma unroll
            for (int m = 0; m < 2; m++)
#pragma unroll
                for (int r = 0; r < 4; r++) {
                    int row = t0 + m * 16 + qd * 4 + r;
#pragma unroll
                    for (int nn = 0; nn < 4; nn++) {
                        int col = hd0 + w * 64 + nn * 16 + l15;
                        atomicAdd(&h_buf[(size_t)row * DMODEL + col], acc[m][nn][r]);
                        acc[m][nn][r] = 0.f;
                    }
                }
            if (tid < 32) {     // rs_acc complete since the mid-unit barrier
                atomicAdd(&rs_buf[h * SEQ + t0 + tid], rs_acc[tid]);
                rs_acc[tid] = 0.f;
            }
        }
        if (--remaining == 0) break;
        tile = ntile; js = njs; needQ = nq;
    }
}

// ------------------------------------- finish: normalizer scale + per-head LN
__global__ __launch_bounds__(256) void k_finish(const float* __restrict__ h_buf,
                                                const float* __restrict__ rs_buf,
                                                const float* __restrict__ nfl_g,
                                                const void* __restrict__ ow,
                                                const int* flag, void* out) {
    const int wv = threadIdx.x >> 6, lane = threadIdx.x & 63;
    const int rid = blockIdx.x * 4 + wv;       // 0..16383
    const int s = rid >> 3, h = rid & 7;
    const int bf = *(volatile const int*)flag;
    float rs  = rs_buf[h * SEQ + s];
    float nfl = nfl_g[h * SEQ + s];
    float sc  = 1.0f / (fmaxf(fabsf(rs), nfl) + 1e-6f);
    size_t base = (size_t)s * DMODEL + h * DHEAD + lane * 4;
    v4f hv = *(const v4f*)(h_buf + base);
#pragma unroll
    for (int j = 0; j < 4; j++) hv[j] *= sc;
    float sm = hv[0] + hv[1] + hv[2] + hv[3];
    float sq = hv[0] * hv[0] + hv[1] * hv[1] + hv[2] * hv[2] + hv[3] * hv[3];
#pragma unroll
    for (int m = 1; m < 64; m <<= 1) {
        sm += __shfl_xor(sm, m, 64);
        sq += __shfl_xor(sq, m, 64);
    }
    float mean = sm * (1.0f / 256.0f);
    float var  = fmaxf(sq * (1.0f / 256.0f) - mean * mean, 0.0f);
    float rstd = rsqrtf(var + 1e-6f);
    int gi = h * DHEAD + lane * 4;
    float gv[4];
    if (bf) {
        const unsigned short* gp = (const unsigned short*)ow;
#pragma unroll
        for (int j = 0; j < 4; j++) gv[j] = b2f(gp[gi + j]);
    } else {
        const float* gp = (const float*)ow;
#pragma unroll
        for (int j = 0; j < 4; j++) gv[j] = gp[gi + j];
    }
    if (bf) {
        unsigned short* o = (unsigned short*)out + base;
#pragma unroll
        for (int j = 0; j < 4; j++) o[j] = f2b((hv[j] - mean) * rstd * gv[j]);
    } else {
        float* o = (float*)out + base;
#pragma unroll
        for (int j = 0; j < 4; j++) o[j] = (hv[j] - mean) * rstd * gv[j];
    }
}

// ---------------------------------------------------------------------- host
extern "C" void kernel_launch(void* const* d_in, const int* in_sizes, int n_in,
                              void* d_out, int out_size, void* d_ws, size_t ws_size,
                              hipStream_t stream) {
    const void* q   = d_in[0];
    const void* k   = d_in[1];
    const void* v   = d_in[2];
    const void* igk = d_in[3];
    const void* igb = d_in[4];
    const void* fgk = d_in[5];
    const void* fgb = d_in[6];
    const void* ow  = d_in[7];

    char* ws = (char*)d_ws;
    int*   flag   = (int*)(ws + 0);
    // zeroed region (contiguous, one memset): ipre | fpre | rs_buf | h_buf
    float* ipre   = (float*)(ws + 1024);
    float* fpre   = ipre + NHEAD * SEQ;
    float* rs_buf = fpre + NHEAD * SEQ;
    float* h_buf  = rs_buf + NHEAD * SEQ;
    float* a_g    = h_buf + (size_t)SEQ * DMODEL;
    float* amax_g = a_g + NHEAD * SEQ;
    float* nfl_g  = amax_g + NHEAD * SEQ;
    unsigned short* qb = (unsigned short*)(nfl_g + NHEAD * SEQ);
    unsigned short* kb = qb + (size_t)SEQ * DMODEL;
    unsigned short* vT = kb + (size_t)SEQ * DMODEL;

    size_t zbytes = (size_t)(3 * NHEAD * SEQ) * 4 + (size_t)SEQ * DMODEL * 4;
    hipMemsetAsync(ipre, 0, zbytes, stream);
    k_detect<<<1, 256, 0, stream>>>((const unsigned short*)q, flag);
    k_cvt<<<2048, 256, 0, stream>>>(q, k, v, flag, qb, kb, vT);
    k_gates<<<dim3(64, 8), 256, 0, stream>>>(qb, kb, v, igk, fgk, flag, ipre, fpre);
    k_scan<<<8, 256, 0, stream>>>(ipre, fpre, igb, fgb, flag, a_g, amax_g, nfl_g);
    k_main<<<dim3(8, 96), 256, 0, stream>>>(qb, kb, vT, a_g, amax_g, h_buf, rs_buf);
    k_finish<<<4096, 256, 0, stream>>>(h_buf, rs_buf, nfl_g, ow, flag, d_out);
}